// Round 1
// baseline (161.952 us; speedup 1.0000x reference)
//
#include <hip/hip_runtime.h>
#include <hip/hip_cooperative_groups.h>

namespace cg = cooperative_groups;

#define PAD 0
#define CONST_NO 10000
#define Bn 8
#define Sn 64
#define Gn 8
#define Fn 200000
#define Rn 200
#define BMAXn 3
#define KF 64
#define KR 32

#define NBLK 196
#define CHB  1024

// ---- workspace layout (ints) ----
#define OFF_CNTF   0                    // 512: per-state unordered match count
#define OFF_PN     512                  // 64 : per-predicate min(count,64)
#define OFF_PFIRST 1024                 // 64*64: first-64 fact idx per predicate
#define OFF_UF     5120                 // 512*64: unordered fact idx per state

__device__ __forceinline__ bool isv(int x) { return x > CONST_NO; }

// Single fused cooperative kernel:
//   phase 0: zero per-state counters (blocks 0..1)
//   phase 1: blocks [0,196) probe facts vs const-queries;
//            blocks [196,246) collect first-64 facts per predicate
//   phase 2: blocks [0,8) finalize + select (one block per batch)
__global__ __launch_bounds__(256) void fused_kernel(
    const int* __restrict__ goals, const float* __restrict__ ss,
    const int* __restrict__ facts, const float* __restrict__ fsc,
    const int* __restrict__ heads, const int* __restrict__ bodies,
    const int* __restrict__ rlens, const float* __restrict__ rsc,
    int* __restrict__ ws, float* __restrict__ outp)
{
    cg::grid_group grid = cg::this_grid();
    const int t = threadIdx.x;
    const int lane = t & 63, wv = t >> 6;

    // ================= phase 0: zero cntF =================
    {
        const int gid = blockIdx.x * 256 + t;
        if (gid < 512) ws[OFF_CNTF + gid] = 0;
    }
    grid.sync();

    // ================= phase 1: probe / collect =================
    __shared__ int4 qlist[512];
    __shared__ int qcnt[64], qstart[64];
    __shared__ int wave_tot[4];

    if (blockIdx.x < NBLK) {
        // ---------- probe role ----------
        const int B = blockIdx.x;

        if (t < 64) qcnt[t] = 0;
        __syncthreads();

        // stage the 512 queries, bucketed by predicate (const-arg queries only)
        int myPos[2], myQp[2], myQv[2], myQm[2], mySt[2];
        #pragma unroll
        for (int k = 0; k < 2; ++k) {
            const int s = t + k * 256;
            const int* q = goals + s * (Gn * 3);
            const int qp = q[0], qa0 = q[1], qa1 = q[2];
            const bool v0 = isv(qa0), v1 = isv(qa1);
            const bool use = (qp != PAD) && !(v0 && v1);
            myQp[k] = use ? qp : -1;
            myQv[k] = (v0 ? 0 : (qa0 << 14)) | (v1 ? 0 : qa1);
            myQm[k] = (v0 ? 0 : (0x3FFF << 14)) | (v1 ? 0 : 0x3FFF);
            mySt[k] = s;
            myPos[k] = use ? atomicAdd(&qcnt[qp], 1) : -1;
        }
        __syncthreads();
        if (t < 64) {
            const int v = qcnt[t];
            int incl = v;
            #pragma unroll
            for (int off = 1; off < 64; off <<= 1) {
                int n = __shfl_up(incl, off, 64);
                if (t >= off) incl += n;
            }
            qstart[t] = incl - v;
        }
        __syncthreads();
        #pragma unroll
        for (int k = 0; k < 2; ++k)
            if (myQp[k] >= 0)
                qlist[qstart[myQp[k]] + myPos[k]] =
                    make_int4(myQv[k], myQm[k], mySt[k], 0);
        __syncthreads();

        // stream this block's 1024 facts; compare against the predicate bucket
        const int f0 = B * CHB + t * 4;
        int pv[4], pk[4];
        if (f0 + 3 < Fn) {
            const int4* p4 = (const int4*)(facts + 3 * f0);
            int4 a = p4[0], b4 = p4[1], c4 = p4[2];
            pv[0] = a.x;  pk[0] = (a.y  << 14) | a.z;
            pv[1] = a.w;  pk[1] = (b4.x << 14) | b4.y;
            pv[2] = b4.z; pk[2] = (b4.w << 14) | c4.x;
            pv[3] = c4.y; pk[3] = (c4.z << 14) | c4.w;
        } else {
            #pragma unroll
            for (int u = 0; u < 4; ++u) {
                pv[u] = -1; pk[u] = 0;
                if (f0 + u < Fn) {
                    pv[u] = facts[3 * (f0 + u)];
                    pk[u] = (facts[3 * (f0 + u) + 1] << 14) | facts[3 * (f0 + u) + 2];
                }
            }
        }
        #pragma unroll
        for (int u = 0; u < 4; ++u) {
            if (pv[u] >= 0) {
                const int j0 = qstart[pv[u]], j1 = j0 + qcnt[pv[u]];
                for (int j = j0; j < j1; ++j) {
                    const int4 qq = qlist[j];
                    if (((pk[u] ^ qq.x) & qq.y) == 0) {
                        const int pos = atomicAdd(ws + OFF_CNTF + qq.z, 1);
                        if (pos < KF) ws[OFF_UF + qq.z * KF + pos] = f0 + u;
                    }
                }
            }
        }
    } else {
        // ---------- first-64-per-predicate role ----------
        const int p = blockIdx.x - NBLK + 1;       // predicate 1..50

        int total = 0;
        for (int base = 0; base < Fn && total < KF; base += 1024) {
            const int f0 = base + t * 4;
            unsigned mbits = 0;
            if (f0 + 3 < Fn) {
                const int4* p4 = (const int4*)(facts + 3 * f0);
                int4 a = p4[0], b4 = p4[1], c4 = p4[2];
                if (a.x  == p) mbits |= 1u;
                if (a.w  == p) mbits |= 2u;
                if (b4.z == p) mbits |= 4u;
                if (c4.y == p) mbits |= 8u;
            } else {
                #pragma unroll
                for (int u = 0; u < 4; ++u)
                    if (f0 + u < Fn && facts[3 * (f0 + u)] == p) mbits |= (1u << u);
            }
            const int c4n = __popc(mbits);

            int v = c4n;
            #pragma unroll
            for (int off = 1; off < 64; off <<= 1) {
                int n = __shfl_up(v, off, 64);
                if (lane >= off) v += n;
            }
            if (lane == 63) wave_tot[wv] = v;
            __syncthreads();
            int excl = v - c4n;
            #pragma unroll
            for (int w = 0; w < 4; ++w) if (w < wv) excl += wave_tot[w];
            const int ctot = wave_tot[0] + wave_tot[1] + wave_tot[2] + wave_tot[3];

            int pos = total + excl;
            #pragma unroll
            for (int u = 0; u < 4; ++u) {
                if (mbits & (1u << u)) {
                    if (pos < KF) ws[OFF_PFIRST + p * 64 + pos] = f0 + u;
                    pos++;
                }
            }
            total += ctot;
            __syncthreads();
        }
        if (t == 0) ws[OFF_PN + p] = (total < KF) ? total : KF;
    }

    __threadfence();
    grid.sync();

    // ================= phase 2: finalize + select =================
    if (blockIdx.x < Bn) {
        __shared__ int sfx[Sn * 64];        // 16 KB: sorted fact idx (const states)
        __shared__ int seg[4][Sn][16];      // 16 KB: rule segments (50 rules each)
        __shared__ int segc[4][Sn];
        __shared__ int hds[Rn * 3];
        __shared__ int pref[Sn + 1];
        __shared__ int nfs[Sn], nrs[Sn], vvf[Sn], qps[Sn];

        const int b = blockIdx.x;

        for (int k = t; k < Rn * 3; k += 256) hds[k] = heads[k];
        segc[wv][lane] = 0;   // 4*64 == 256 == blockDim
        __syncthreads();

        // rules: wave wv checks rules [wv*50, wv*50+50) for state s=lane
        {
            const int s = lane;
            const int* q = goals + (b * Sn + s) * (Gn * 3);
            const int qp = q[0], qa0 = q[1], qa1 = q[2];
            const bool v0 = isv(qa0), v1 = isv(qa1);
            const bool active = (qp != PAD);
            int cnt = 0;
            const int r0 = wv * 50;
            for (int r = r0; r < r0 + 50; ++r) {
                const int h0 = hds[3 * r], h1 = hds[3 * r + 1], h2 = hds[3 * r + 2];
                if (active && h0 == qp && (isv(h1) || v0 || qa0 == h1)
                                       && (isv(h2) || v1 || qa1 == h2)) {
                    if (cnt < 16) seg[wv][s][cnt] = r;
                    cnt++;
                }
            }
            segc[wv][s] = (cnt < 16) ? cnt : 16;
        }
        __syncthreads();

        // per-state fact lists + prefix
        if (t < Sn) {
            const int s = t;
            const int* q = goals + (b * Sn + s) * (Gn * 3);
            const int qp = q[0], qa0 = q[1], qa1 = q[2];
            const bool v0 = isv(qa0), v1 = isv(qa1);
            const bool active = (qp != PAD);
            const bool vv = active && v0 && v1;
            int nf = 0;
            if (vv) {
                nf = ws[OFF_PN + qp];
            } else if (active) {
                int c = ws[OFF_CNTF + b * Sn + s];
                if (c > KF) c = KF;
                for (int j = 0; j < c; ++j)
                    sfx[s * 64 + j] = ws[OFF_UF + (b * Sn + s) * KF + j];
                // insertion sort ascending (reference order = ascending fact idx)
                for (int a = 1; a < c; ++a) {
                    const int key = sfx[s * 64 + a];
                    int m = a - 1;
                    while (m >= 0 && sfx[s * 64 + m] > key) {
                        sfx[s * 64 + m + 1] = sfx[s * 64 + m];
                        m--;
                    }
                    sfx[s * 64 + m + 1] = key;
                }
                nf = c;
            }
            nfs[s] = nf;
            vvf[s] = vv ? 1 : 0;
            qps[s] = qp;
            int nr = segc[0][s] + segc[1][s] + segc[2][s] + segc[3][s];
            if (nr > KR) nr = KR;
            nrs[s] = nr;

            int incl = nf + nr;
            #pragma unroll
            for (int off = 1; off < 64; off <<= 1) {
                int n = __shfl_up(incl, off, 64);
                if (t >= off) incl += n;
            }
            pref[s + 1] = incl;
            if (s == 0) pref[0] = 0;
        }
        __syncthreads();
        const int total = pref[Sn];

        // emit goals: 64 slots x 8 positions = 512 items, 2 per thread
        for (int item = t; item < Sn * Gn; item += 256) {
            const int i = item >> 3, g = item & 7;
            int trip[3] = {PAD, PAD, PAD};
            if (i < total) {
                int lo = 0, hi = Sn - 1;
                while (lo < hi) {
                    const int mid = (lo + hi) >> 1;
                    if (pref[mid + 1] <= i) lo = mid + 1; else hi = mid;
                }
                const int s = lo, j = i - pref[s];
                const int* q = goals + (b * Sn + s) * (Gn * 3);
                const int qa0 = q[1], qa1 = q[2];
                if (j < nfs[s]) {
                    const int fi = vvf[s] ? ws[OFF_PFIRST + qps[s] * 64 + j]
                                          : sfx[s * 64 + j];
                    const int f1 = facts[3 * fi + 1], f2 = facts[3 * fi + 2];
                    if (g >= 1) {
                        #pragma unroll
                        for (int c = 0; c < 3; ++c) {
                            int x = q[g * 3 + c];
                            if (isv(qa0) && x == qa0) x = f1;
                            else if (isv(qa1) && x == qa1) x = f2;
                            trip[c] = x;
                        }
                    }
                } else {
                    int jr = j - nfs[s];
                    int wz = 0;
                    while (jr >= segc[wz][s]) { jr -= segc[wz][s]; wz++; }
                    const int ri = seg[wz][s][jr];
                    const int h1 = hds[3 * ri + 1], h2 = hds[3 * ri + 2];
                    const int len = rlens[ri];
                    if (g < BMAXn) {
                        if (g < len) {
                            #pragma unroll
                            for (int c = 0; c < 3; ++c) {
                                int x = bodies[(ri * BMAXn + g) * 3 + c];
                                if (isv(h1) && x == h1) x = qa0;
                                if (isv(h2) && x == h2) x = qa1;
                                trip[c] = x;
                            }
                        }
                    } else {
                        trip[0] = q[(g - 2) * 3 + 0];
                        trip[1] = q[(g - 2) * 3 + 1];
                        trip[2] = q[(g - 2) * 3 + 2];
                    }
                }
            }
            float* o = outp + ((b * Sn + i) * Gn + g) * 3;
            o[0] = (float)trip[0];
            o[1] = (float)trip[1];
            o[2] = (float)trip[2];
        }

        // scores
        if (t < Sn) {
            const int i = t;
            float sc = 0.f;
            if (i < total) {
                int lo = 0, hi = Sn - 1;
                while (lo < hi) {
                    const int mid = (lo + hi) >> 1;
                    if (pref[mid + 1] <= i) lo = mid + 1; else hi = mid;
                }
                const int s = lo, j = i - pref[s];
                const float stt = ss[b * Sn + s];
                if (j < nfs[s]) {
                    const int fi = vvf[s] ? ws[OFF_PFIRST + qps[s] * 64 + j]
                                          : sfx[s * 64 + j];
                    sc = stt * fsc[fi];
                } else {
                    int jr = j - nfs[s];
                    int wz = 0;
                    while (jr >= segc[wz][s]) { jr -= segc[wz][s]; wz++; }
                    sc = stt * rsc[seg[wz][s][jr]];
                }
            }
            outp[Bn * Sn * Gn * 3 + b * Sn + t] = sc;
        }
    }
}

extern "C" void kernel_launch(void* const* d_in, const int* in_sizes, int n_in,
                              void* d_out, int out_size, void* d_ws, size_t ws_size,
                              hipStream_t stream) {
    const int*   goals  = (const int*)  d_in[0];
    const float* ss     = (const float*)d_in[1];
    const int*   facts  = (const int*)  d_in[2];
    const float* fsc    = (const float*)d_in[3];
    const int*   heads  = (const int*)  d_in[4];
    const int*   bodies = (const int*)  d_in[5];
    const int*   rlens  = (const int*)  d_in[6];
    const float* rsc    = (const float*)d_in[7];
    int*   ws   = (int*)d_ws;
    float* outp = (float*)d_out;

    void* args[] = {
        (void*)&goals, (void*)&ss, (void*)&facts, (void*)&fsc,
        (void*)&heads, (void*)&bodies, (void*)&rlens, (void*)&rsc,
        (void*)&ws, (void*)&outp
    };
    hipLaunchCooperativeKernel((void*)fused_kernel, dim3(NBLK + 50), dim3(256),
                               args, 0, stream);
}

// Round 2
// 96.307 us; speedup vs baseline: 1.6816x; 1.6816x over previous
//
#include <hip/hip_runtime.h>

#define PAD 0
#define CONST_NO 10000
#define Bn 8
#define Sn 64
#define Gn 8
#define Fn 200000
#define Rn 200
#define BMAXn 3
#define KF 64
#define KR 32

#define NBLK 196
#define CHB  1024

// ---- workspace layout (ints) ----
#define OFF_CNTF   0                    // 512: per-state unordered match count
#define OFF_PN     512                  // 64 : per-predicate min(count,64)
#define OFF_PFIRST 1024                 // 64*64: first-64 fact idx per predicate
#define OFF_UF     5120                 // 512*64: unordered fact idx per state
#define OFF_QSTART 37888                // 64 : bucket start per predicate
#define OFF_QCNT   37952                // 64 : bucket count per predicate
#define OFF_QLIST  38016                // 512*4: bucketed query list (int4), 16B aligned

__device__ __forceinline__ bool isv(int x) { return x > CONST_NO; }

// ---------- setup: block 0 zeroes counters + builds bucketed query list;
//                   blocks 1..50 collect first-64 facts per predicate ----------
__global__ __launch_bounds__(256) void setup_kernel(
    const int* __restrict__ goals, const int* __restrict__ facts,
    int* __restrict__ ws)
{
    const int t = threadIdx.x;
    const int lane = t & 63, wv = t >> 6;

    if (blockIdx.x == 0) {
        // ---- zero per-state counters ----
        ws[OFF_CNTF + t] = 0;
        ws[OFF_CNTF + 256 + t] = 0;

        // ---- build predicate-bucketed query list (once for all probe blocks) ----
        __shared__ int4 qlist[512];
        __shared__ int qcnt[64], qstart[64];
        if (t < 64) qcnt[t] = 0;
        __syncthreads();

        int myPos[2], myQp[2], myQv[2], myQm[2], mySt[2];
        #pragma unroll
        for (int k = 0; k < 2; ++k) {
            const int s = t + k * 256;
            const int* q = goals + s * (Gn * 3);
            const int qp = q[0], qa0 = q[1], qa1 = q[2];
            const bool v0 = isv(qa0), v1 = isv(qa1);
            const bool use = (qp != PAD) && !(v0 && v1);
            myQp[k] = use ? qp : -1;
            myQv[k] = (v0 ? 0 : (qa0 << 14)) | (v1 ? 0 : qa1);
            myQm[k] = (v0 ? 0 : (0x3FFF << 14)) | (v1 ? 0 : 0x3FFF);
            mySt[k] = s;
            myPos[k] = use ? atomicAdd(&qcnt[qp], 1) : -1;
        }
        __syncthreads();
        if (t < 64) {
            const int v = qcnt[t];
            int incl = v;
            #pragma unroll
            for (int off = 1; off < 64; off <<= 1) {
                int n = __shfl_up(incl, off, 64);
                if (t >= off) incl += n;
            }
            qstart[t] = incl - v;
        }
        __syncthreads();
        #pragma unroll
        for (int k = 0; k < 2; ++k)
            if (myQp[k] >= 0)
                qlist[qstart[myQp[k]] + myPos[k]] =
                    make_int4(myQv[k], myQm[k], mySt[k], 0);
        __syncthreads();

        if (t < 64) {
            ws[OFF_QSTART + t] = qstart[t];
            ws[OFF_QCNT + t]   = qcnt[t];
        }
        int4* dst = (int4*)(ws + OFF_QLIST);
        dst[t]       = qlist[t];
        dst[t + 256] = qlist[t + 256];
    } else {
        // ---- first-64-per-predicate role: p = blockIdx.x in 1..50 ----
        __shared__ int wave_tot[4];
        const int p = blockIdx.x;

        int total = 0;
        for (int base = 0; base < Fn && total < KF; base += 1024) {
            const int f0 = base + t * 4;
            unsigned mbits = 0;
            if (f0 + 3 < Fn) {
                const int4* p4 = (const int4*)(facts + 3 * f0);
                int4 a = p4[0], b4 = p4[1], c4 = p4[2];
                if (a.x  == p) mbits |= 1u;
                if (a.w  == p) mbits |= 2u;
                if (b4.z == p) mbits |= 4u;
                if (c4.y == p) mbits |= 8u;
            } else {
                #pragma unroll
                for (int u = 0; u < 4; ++u)
                    if (f0 + u < Fn && facts[3 * (f0 + u)] == p) mbits |= (1u << u);
            }
            const int c4n = __popc(mbits);

            int v = c4n;
            #pragma unroll
            for (int off = 1; off < 64; off <<= 1) {
                int n = __shfl_up(v, off, 64);
                if (lane >= off) v += n;
            }
            if (lane == 63) wave_tot[wv] = v;
            __syncthreads();
            int excl = v - c4n;
            #pragma unroll
            for (int w = 0; w < 4; ++w) if (w < wv) excl += wave_tot[w];
            const int ctot = wave_tot[0] + wave_tot[1] + wave_tot[2] + wave_tot[3];

            int pos = total + excl;
            #pragma unroll
            for (int u = 0; u < 4; ++u) {
                if (mbits & (1u << u)) {
                    if (pos < KF) ws[OFF_PFIRST + p * 64 + pos] = f0 + u;
                    pos++;
                }
            }
            total += ctot;
            __syncthreads();
        }
        if (t == 0) ws[OFF_PN + p] = (total < KF) ? total : KF;
    }
}

// ---------- probe: 196 uniform blocks stream facts vs precomputed qlist ----------
__global__ __launch_bounds__(256) void probe_kernel(
    const int* __restrict__ facts, int* __restrict__ ws)
{
    __shared__ int4 qlist[512];
    __shared__ int qstart[64], qcnt[64];
    const int t = threadIdx.x;
    const int B = blockIdx.x;

    {
        const int4* src = (const int4*)(ws + OFF_QLIST);
        qlist[t]       = src[t];
        qlist[t + 256] = src[t + 256];
        if (t < 64) {
            qstart[t] = ws[OFF_QSTART + t];
            qcnt[t]   = ws[OFF_QCNT + t];
        }
    }
    __syncthreads();

    // stream this block's 1024 facts; compare against the predicate bucket
    const int f0 = B * CHB + t * 4;
    int pv[4], pk[4];
    if (f0 + 3 < Fn) {
        const int4* p4 = (const int4*)(facts + 3 * f0);
        int4 a = p4[0], b4 = p4[1], c4 = p4[2];
        pv[0] = a.x;  pk[0] = (a.y  << 14) | a.z;
        pv[1] = a.w;  pk[1] = (b4.x << 14) | b4.y;
        pv[2] = b4.z; pk[2] = (b4.w << 14) | c4.x;
        pv[3] = c4.y; pk[3] = (c4.z << 14) | c4.w;
    } else {
        #pragma unroll
        for (int u = 0; u < 4; ++u) {
            pv[u] = -1; pk[u] = 0;
            if (f0 + u < Fn) {
                pv[u] = facts[3 * (f0 + u)];
                pk[u] = (facts[3 * (f0 + u) + 1] << 14) | facts[3 * (f0 + u) + 2];
            }
        }
    }
    #pragma unroll
    for (int u = 0; u < 4; ++u) {
        if (pv[u] >= 0) {
            const int j0 = qstart[pv[u]], j1 = j0 + qcnt[pv[u]];
            for (int j = j0; j < j1; ++j) {
                const int4 qq = qlist[j];
                if (((pk[u] ^ qq.x) & qq.y) == 0) {
                    const int pos = atomicAdd(ws + OFF_CNTF + qq.z, 1);
                    if (pos < KF) ws[OFF_UF + qq.z * KF + pos] = f0 + u;
                }
            }
        }
    }
}

// ---------- finalize + select: one block per batch ----------
__global__ __launch_bounds__(256) void finalize_kernel(
    const int* __restrict__ goals, const float* __restrict__ ss,
    const int* __restrict__ facts, const float* __restrict__ fsc,
    const int* __restrict__ heads, const int* __restrict__ bodies,
    const int* __restrict__ rlens, const float* __restrict__ rsc,
    const int* __restrict__ ws, float* __restrict__ outp)
{
    __shared__ int sfx[Sn * 64];        // 16 KB: sorted fact idx (const states)
    __shared__ int seg[4][Sn][16];      // 16 KB: rule segments (50 rules each)
    __shared__ int segc[4][Sn];
    __shared__ int hds[Rn * 3];
    __shared__ int pref[Sn + 1];
    __shared__ int nfs[Sn], vvf[Sn], qps[Sn];

    const int b = blockIdx.x, t = threadIdx.x;
    const int lane = t & 63, wv = t >> 6;

    for (int k = t; k < Rn * 3; k += 256) hds[k] = heads[k];
    segc[wv][lane] = 0;   // 4*64 == 256 == blockDim
    __syncthreads();

    // rules: wave wv checks rules [wv*50, wv*50+50) for state s=lane
    {
        const int s = lane;
        const int* q = goals + (b * Sn + s) * (Gn * 3);
        const int qp = q[0], qa0 = q[1], qa1 = q[2];
        const bool v0 = isv(qa0), v1 = isv(qa1);
        const bool active = (qp != PAD);
        int cnt = 0;
        const int r0 = wv * 50;
        for (int r = r0; r < r0 + 50; ++r) {
            const int h0 = hds[3 * r], h1 = hds[3 * r + 1], h2 = hds[3 * r + 2];
            if (active && h0 == qp && (isv(h1) || v0 || qa0 == h1)
                                   && (isv(h2) || v1 || qa1 == h2)) {
                if (cnt < 16) seg[wv][s][cnt] = r;
                cnt++;
            }
        }
        segc[wv][s] = (cnt < 16) ? cnt : 16;
    }
    __syncthreads();

    // per-state fact lists + prefix
    if (t < Sn) {
        const int s = t;
        const int* q = goals + (b * Sn + s) * (Gn * 3);
        const int qp = q[0], qa0 = q[1], qa1 = q[2];
        const bool v0 = isv(qa0), v1 = isv(qa1);
        const bool active = (qp != PAD);
        const bool vv = active && v0 && v1;
        int nf = 0;
        if (vv) {
            nf = ws[OFF_PN + qp];
        } else if (active) {
            int c = ws[OFF_CNTF + b * Sn + s];
            if (c > KF) c = KF;
            for (int j = 0; j < c; ++j)
                sfx[s * 64 + j] = ws[OFF_UF + (b * Sn + s) * KF + j];
            // insertion sort ascending (reference order = ascending fact idx)
            for (int a = 1; a < c; ++a) {
                const int key = sfx[s * 64 + a];
                int m = a - 1;
                while (m >= 0 && sfx[s * 64 + m] > key) {
                    sfx[s * 64 + m + 1] = sfx[s * 64 + m];
                    m--;
                }
                sfx[s * 64 + m + 1] = key;
            }
            nf = c;
        }
        nfs[s] = nf;
        vvf[s] = vv ? 1 : 0;
        qps[s] = qp;
        int nr = segc[0][s] + segc[1][s] + segc[2][s] + segc[3][s];
        if (nr > KR) nr = KR;

        int incl = nf + nr;
        #pragma unroll
        for (int off = 1; off < 64; off <<= 1) {
            int n = __shfl_up(incl, off, 64);
            if (t >= off) incl += n;
        }
        pref[s + 1] = incl;
        if (s == 0) pref[0] = 0;
    }
    __syncthreads();
    const int total = pref[Sn];

    // emit goals: 64 slots x 8 positions = 512 items, 2 per thread
    for (int item = t; item < Sn * Gn; item += 256) {
        const int i = item >> 3, g = item & 7;
        int trip[3] = {PAD, PAD, PAD};
        if (i < total) {
            int lo = 0, hi = Sn - 1;
            while (lo < hi) {
                const int mid = (lo + hi) >> 1;
                if (pref[mid + 1] <= i) lo = mid + 1; else hi = mid;
            }
            const int s = lo, j = i - pref[s];
            const int* q = goals + (b * Sn + s) * (Gn * 3);
            const int qa0 = q[1], qa1 = q[2];
            if (j < nfs[s]) {
                const int fi = vvf[s] ? ws[OFF_PFIRST + qps[s] * 64 + j]
                                      : sfx[s * 64 + j];
                const int f1 = facts[3 * fi + 1], f2 = facts[3 * fi + 2];
                if (g >= 1) {
                    #pragma unroll
                    for (int c = 0; c < 3; ++c) {
                        int x = q[g * 3 + c];
                        if (isv(qa0) && x == qa0) x = f1;
                        else if (isv(qa1) && x == qa1) x = f2;
                        trip[c] = x;
                    }
                }
            } else {
                int jr = j - nfs[s];
                int wz = 0;
                while (jr >= segc[wz][s]) { jr -= segc[wz][s]; wz++; }
                const int ri = seg[wz][s][jr];
                const int h1 = hds[3 * ri + 1], h2 = hds[3 * ri + 2];
                const int len = rlens[ri];
                if (g < BMAXn) {
                    if (g < len) {
                        #pragma unroll
                        for (int c = 0; c < 3; ++c) {
                            int x = bodies[(ri * BMAXn + g) * 3 + c];
                            if (isv(h1) && x == h1) x = qa0;
                            if (isv(h2) && x == h2) x = qa1;
                            trip[c] = x;
                        }
                    }
                } else {
                    trip[0] = q[(g - 2) * 3 + 0];
                    trip[1] = q[(g - 2) * 3 + 1];
                    trip[2] = q[(g - 2) * 3 + 2];
                }
            }
        }
        float* o = outp + ((b * Sn + i) * Gn + g) * 3;
        o[0] = (float)trip[0];
        o[1] = (float)trip[1];
        o[2] = (float)trip[2];
    }

    // scores
    if (t < Sn) {
        const int i = t;
        float sc = 0.f;
        if (i < total) {
            int lo = 0, hi = Sn - 1;
            while (lo < hi) {
                const int mid = (lo + hi) >> 1;
                if (pref[mid + 1] <= i) lo = mid + 1; else hi = mid;
            }
            const int s = lo, j = i - pref[s];
            const float stt = ss[b * Sn + s];
            if (j < nfs[s]) {
                const int fi = vvf[s] ? ws[OFF_PFIRST + qps[s] * 64 + j]
                                      : sfx[s * 64 + j];
                sc = stt * fsc[fi];
            } else {
                int jr = j - nfs[s];
                int wz = 0;
                while (jr >= segc[wz][s]) { jr -= segc[wz][s]; wz++; }
                sc = stt * rsc[seg[wz][s][jr]];
            }
        }
        outp[Bn * Sn * Gn * 3 + b * Sn + t] = sc;
    }
}

extern "C" void kernel_launch(void* const* d_in, const int* in_sizes, int n_in,
                              void* d_out, int out_size, void* d_ws, size_t ws_size,
                              hipStream_t stream) {
    const int*   goals  = (const int*)  d_in[0];
    const float* ss     = (const float*)d_in[1];
    const int*   facts  = (const int*)  d_in[2];
    const float* fsc    = (const float*)d_in[3];
    const int*   heads  = (const int*)  d_in[4];
    const int*   bodies = (const int*)  d_in[5];
    const int*   rlens  = (const int*)  d_in[6];
    const float* rsc    = (const float*)d_in[7];
    int*   ws   = (int*)d_ws;
    float* outp = (float*)d_out;

    setup_kernel   <<<51,   256, 0, stream>>>(goals, facts, ws);
    probe_kernel   <<<NBLK, 256, 0, stream>>>(facts, ws);
    finalize_kernel<<<Bn,   256, 0, stream>>>(goals, ss, facts, fsc, heads,
                                              bodies, rlens, rsc, ws, outp);
}

// Round 3
// 95.806 us; speedup vs baseline: 1.6904x; 1.0052x over previous
//
#include <hip/hip_runtime.h>

#define PAD 0
#define CONST_NO 10000
#define Bn 8
#define Sn 64
#define Gn 8
#define Fn 200000
#define Rn 200
#define BMAXn 3
#define KF 64
#define KR 32

#define NBLK 196
#define CHB  1024
#define CAP  1024          // per-block match buffer capacity (entries)
#define ENTCAP 2048        // finalize compaction capacity (entries)

// ---- workspace layout (ints); NOTHING needs pre-zeroing ----
#define OFF_PN     0                    // 64 : per-predicate min(count,64)
#define OFF_PFIRST 64                   // 64*64: first-64 fact idx per predicate
#define OFF_BCNT   4160                 // 196: per-block match count (written unconditionally)
#define OFF_GBUF   4360                 // 196*CAP: per-block packed matches (state<<18 | fact)

__device__ __forceinline__ bool isv(int x) { return x > CONST_NO; }

// ---------- fused: blocks [0,196) probe facts vs const-queries (compact per-block output);
//                   blocks [196,246) collect first-64 per predicate ----------
__global__ __launch_bounds__(256) void probe_kernel(
    const int* __restrict__ goals, const int* __restrict__ facts,
    int* __restrict__ ws)
{
    const int t = threadIdx.x;
    const int lane = t & 63, wv = t >> 6;

    if (blockIdx.x < NBLK) {
        // ================= probe role =================
        __shared__ int4 qlist[512];
        __shared__ int qcnt[64], qstart[64];
        __shared__ int wtot[4];
        const int B = blockIdx.x;

        if (t < 64) qcnt[t] = 0;
        __syncthreads();

        // stage the 512 queries, bucketed by predicate (const-arg queries only)
        int myPos[2], myQp[2], myQv[2], myQm[2];
        #pragma unroll
        for (int k = 0; k < 2; ++k) {
            const int s = t + k * 256;
            const int* q = goals + s * (Gn * 3);
            const int qp = q[0], qa0 = q[1], qa1 = q[2];
            const bool v0 = isv(qa0), v1 = isv(qa1);
            const bool use = (qp != PAD) && !(v0 && v1);
            myQp[k] = use ? qp : -1;
            myQv[k] = (v0 ? 0 : (qa0 << 14)) | (v1 ? 0 : qa1);
            myQm[k] = (v0 ? 0 : (0x3FFF << 14)) | (v1 ? 0 : 0x3FFF);
            myPos[k] = use ? atomicAdd(&qcnt[qp], 1) : -1;
        }
        __syncthreads();
        if (t < 64) {
            const int v = qcnt[t];
            int incl = v;
            #pragma unroll
            for (int off = 1; off < 64; off <<= 1) {
                int n = __shfl_up(incl, off, 64);
                if (t >= off) incl += n;
            }
            qstart[t] = incl - v;
        }
        __syncthreads();
        #pragma unroll
        for (int k = 0; k < 2; ++k)
            if (myQp[k] >= 0)
                qlist[qstart[myQp[k]] + myPos[k]] =
                    make_int4(myQv[k], myQm[k], t + k * 256, 0);
        __syncthreads();

        // load this block's 1024 facts
        const int f0 = B * CHB + t * 4;
        int pv[4], pk[4];
        if (f0 + 3 < Fn) {
            const int4* p4 = (const int4*)(facts + 3 * f0);
            int4 a = p4[0], b4 = p4[1], c4 = p4[2];
            pv[0] = a.x;  pk[0] = (a.y  << 14) | a.z;
            pv[1] = a.w;  pk[1] = (b4.x << 14) | b4.y;
            pv[2] = b4.z; pk[2] = (b4.w << 14) | c4.x;
            pv[3] = c4.y; pk[3] = (c4.z << 14) | c4.w;
        } else {
            #pragma unroll
            for (int u = 0; u < 4; ++u) {
                pv[u] = -1; pk[u] = 0;
                if (f0 + u < Fn) {
                    pv[u] = facts[3 * (f0 + u)];
                    pk[u] = (facts[3 * (f0 + u) + 1] << 14) | facts[3 * (f0 + u) + 2];
                }
            }
        }

        // pass 1: count matches
        int myCnt = 0;
        #pragma unroll
        for (int u = 0; u < 4; ++u) {
            if (pv[u] >= 0) {
                const int j0 = qstart[pv[u]], j1 = j0 + qcnt[pv[u]];
                for (int j = j0; j < j1; ++j) {
                    const int4 qq = qlist[j];
                    if (((pk[u] ^ qq.x) & qq.y) == 0) myCnt++;
                }
            }
        }

        // block exclusive prefix of per-thread counts
        int incl = myCnt;
        #pragma unroll
        for (int off = 1; off < 64; off <<= 1) {
            int n = __shfl_up(incl, off, 64);
            if (lane >= off) incl += n;
        }
        if (lane == 63) wtot[wv] = incl;
        __syncthreads();
        int excl = incl - myCnt;
        #pragma unroll
        for (int w = 0; w < 4; ++w) if (w < wv) excl += wtot[w];
        const int btot = wtot[0] + wtot[1] + wtot[2] + wtot[3];
        if (t == 0) ws[OFF_BCNT + B] = (btot < CAP) ? btot : CAP;

        // pass 2: only threads with matches re-scan and emit packed entries.
        // Order: thread asc (fact asc) x fact asc -> per-state lists ascend by fact idx.
        if (myCnt > 0) {
            int* dst = ws + OFF_GBUF + B * CAP;
            int k = excl;
            #pragma unroll
            for (int u = 0; u < 4; ++u) {
                if (pv[u] >= 0) {
                    const int j0 = qstart[pv[u]], j1 = j0 + qcnt[pv[u]];
                    for (int j = j0; j < j1; ++j) {
                        const int4 qq = qlist[j];
                        if (((pk[u] ^ qq.x) & qq.y) == 0) {
                            if (k < CAP) dst[k] = (qq.z << 18) | (f0 + u);
                            k++;
                        }
                    }
                }
            }
        }
    } else {
        // ================= first-64-per-predicate role =================
        __shared__ int wave_tot[4];
        const int p = blockIdx.x - NBLK + 1;       // predicate 1..50

        int total = 0;
        for (int base = 0; base < Fn && total < KF; base += 1024) {
            const int f0 = base + t * 4;
            unsigned mbits = 0;
            if (f0 + 3 < Fn) {
                const int4* p4 = (const int4*)(facts + 3 * f0);
                int4 a = p4[0], b4 = p4[1], c4 = p4[2];
                if (a.x  == p) mbits |= 1u;
                if (a.w  == p) mbits |= 2u;
                if (b4.z == p) mbits |= 4u;
                if (c4.y == p) mbits |= 8u;
            } else {
                #pragma unroll
                for (int u = 0; u < 4; ++u)
                    if (f0 + u < Fn && facts[3 * (f0 + u)] == p) mbits |= (1u << u);
            }
            const int c4n = __popc(mbits);

            int v = c4n;
            #pragma unroll
            for (int off = 1; off < 64; off <<= 1) {
                int n = __shfl_up(v, off, 64);
                if (lane >= off) v += n;
            }
            if (lane == 63) wave_tot[wv] = v;
            __syncthreads();
            int excl = v - c4n;
            #pragma unroll
            for (int w = 0; w < 4; ++w) if (w < wv) excl += wave_tot[w];
            const int ctot = wave_tot[0] + wave_tot[1] + wave_tot[2] + wave_tot[3];

            int pos = total + excl;
            #pragma unroll
            for (int u = 0; u < 4; ++u) {
                if (mbits & (1u << u)) {
                    if (pos < KF) ws[OFF_PFIRST + p * 64 + pos] = f0 + u;
                    pos++;
                }
            }
            total += ctot;
            __syncthreads();
        }
        if (t == 0) ws[OFF_PN + p] = (total < KF) ? total : KF;
    }
}

// ---------- finalize + select: one block per batch ----------
__global__ __launch_bounds__(256) void finalize_kernel(
    const int* __restrict__ goals, const float* __restrict__ ss,
    const int* __restrict__ facts, const float* __restrict__ fsc,
    const int* __restrict__ heads, const int* __restrict__ bodies,
    const int* __restrict__ rlens, const float* __restrict__ rsc,
    const int* __restrict__ ws, float* __restrict__ outp)
{
    __shared__ int sfx[Sn * 64];        // 16 KB: per-state fact idx (ascending, pre-merged)
    __shared__ int seg[4][Sn][16];      // 16 KB: rule segments (50 rules each)
    __shared__ int segc[4][Sn];
    __shared__ int hds[Rn * 3];
    __shared__ int pref[Sn + 1];
    __shared__ int nfs[Sn], vvf[Sn], qps[Sn];
    __shared__ int ent[ENTCAP];         // 8 KB: compacted global match entries
    __shared__ int bco[NBLK];           // per-block entry offsets
    __shared__ int wsum[4];

    const int b = blockIdx.x, t = threadIdx.x;
    const int lane = t & 63, wv = t >> 6;

    for (int k = t; k < Rn * 3; k += 256) hds[k] = heads[k];
    segc[wv][lane] = 0;   // 4*64 == 256 == blockDim

    // load per-block match counts + wave-level scan
    const int bc = (t < NBLK) ? ws[OFF_BCNT + t] : 0;
    int binc = bc;
    #pragma unroll
    for (int off = 1; off < 64; off <<= 1) {
        int n = __shfl_up(binc, off, 64);
        if (lane >= off) binc += n;
    }
    if (lane == 63) wsum[wv] = binc;
    __syncthreads();

    int bexc = binc - bc;
    #pragma unroll
    for (int w = 0; w < 4; ++w) if (w < wv) bexc += wsum[w];
    int TT = wsum[0] + wsum[1] + wsum[2] + wsum[3];
    if (TT > ENTCAP) TT = ENTCAP;
    if (t < NBLK) bco[t] = bexc;

    // compact all per-block match lists into LDS (order: block asc, in-block asc)
    if (t < NBLK) {
        const int* src = ws + OFF_GBUF + t * CAP;
        for (int k = 0; k < bc; ++k) {
            const int o = bexc + k;
            if (o < ENTCAP) ent[o] = src[k];
        }
    }

    // rules: wave wv checks rules [wv*50, wv*50+50) for state s=lane
    {
        const int s = lane;
        const int* q = goals + (b * Sn + s) * (Gn * 3);
        const int qp = q[0], qa0 = q[1], qa1 = q[2];
        const bool v0 = isv(qa0), v1 = isv(qa1);
        const bool active = (qp != PAD);
        int cnt = 0;
        const int r0 = wv * 50;
        for (int r = r0; r < r0 + 50; ++r) {
            const int h0 = hds[3 * r], h1 = hds[3 * r + 1], h2 = hds[3 * r + 2];
            if (active && h0 == qp && (isv(h1) || v0 || qa0 == h1)
                                   && (isv(h2) || v1 || qa1 == h2)) {
                if (cnt < 16) seg[wv][s][cnt] = r;
                cnt++;
            }
        }
        segc[wv][s] = (cnt < 16) ? cnt : 16;
    }
    __syncthreads();

    // per-state fact lists (filter compacted entries, already ascending) + prefix
    if (t < Sn) {
        const int s = t;
        const int* q = goals + (b * Sn + s) * (Gn * 3);
        const int qp = q[0], qa0 = q[1], qa1 = q[2];
        const bool v0 = isv(qa0), v1 = isv(qa1);
        const bool active = (qp != PAD);
        const bool vv = active && v0 && v1;
        int nf = 0;
        if (vv) {
            nf = ws[OFF_PN + qp];
        } else if (active) {
            const int gs = b * Sn + s;          // global state id as packed in entries
            for (int j = 0; j < TT; ++j) {
                const int e = ent[j];
                if ((e >> 18) == gs) {
                    if (nf < KF) sfx[s * 64 + nf] = e & 0x3FFFF;
                    nf++;
                }
            }
            if (nf > KF) nf = KF;
        }
        nfs[s] = nf;
        vvf[s] = vv ? 1 : 0;
        qps[s] = qp;
        int nr = segc[0][s] + segc[1][s] + segc[2][s] + segc[3][s];
        if (nr > KR) nr = KR;

        int incl = nf + nr;
        #pragma unroll
        for (int off = 1; off < 64; off <<= 1) {
            int n = __shfl_up(incl, off, 64);
            if (t >= off) incl += n;
        }
        pref[s + 1] = incl;
        if (s == 0) pref[0] = 0;
    }
    __syncthreads();
    const int total = pref[Sn];

    // emit goals: 64 slots x 8 positions = 512 items, 2 per thread
    for (int item = t; item < Sn * Gn; item += 256) {
        const int i = item >> 3, g = item & 7;
        int trip[3] = {PAD, PAD, PAD};
        if (i < total) {
            int lo = 0, hi = Sn - 1;
            while (lo < hi) {
                const int mid = (lo + hi) >> 1;
                if (pref[mid + 1] <= i) lo = mid + 1; else hi = mid;
            }
            const int s = lo, j = i - pref[s];
            const int* q = goals + (b * Sn + s) * (Gn * 3);
            const int qa0 = q[1], qa1 = q[2];
            if (j < nfs[s]) {
                const int fi = vvf[s] ? ws[OFF_PFIRST + qps[s] * 64 + j]
                                      : sfx[s * 64 + j];
                const int f1 = facts[3 * fi + 1], f2 = facts[3 * fi + 2];
                if (g >= 1) {
                    #pragma unroll
                    for (int c = 0; c < 3; ++c) {
                        int x = q[g * 3 + c];
                        if (isv(qa0) && x == qa0) x = f1;
                        else if (isv(qa1) && x == qa1) x = f2;
                        trip[c] = x;
                    }
                }
            } else {
                int jr = j - nfs[s];
                int wz = 0;
                while (jr >= segc[wz][s]) { jr -= segc[wz][s]; wz++; }
                const int ri = seg[wz][s][jr];
                const int h1 = hds[3 * ri + 1], h2 = hds[3 * ri + 2];
                const int len = rlens[ri];
                if (g < BMAXn) {
                    if (g < len) {
                        #pragma unroll
                        for (int c = 0; c < 3; ++c) {
                            int x = bodies[(ri * BMAXn + g) * 3 + c];
                            if (isv(h1) && x == h1) x = qa0;
                            if (isv(h2) && x == h2) x = qa1;
                            trip[c] = x;
                        }
                    }
                } else {
                    trip[0] = q[(g - 2) * 3 + 0];
                    trip[1] = q[(g - 2) * 3 + 1];
                    trip[2] = q[(g - 2) * 3 + 2];
                }
            }
        }
        float* o = outp + ((b * Sn + i) * Gn + g) * 3;
        o[0] = (float)trip[0];
        o[1] = (float)trip[1];
        o[2] = (float)trip[2];
    }

    // scores
    if (t < Sn) {
        const int i = t;
        float sc = 0.f;
        if (i < total) {
            int lo = 0, hi = Sn - 1;
            while (lo < hi) {
                const int mid = (lo + hi) >> 1;
                if (pref[mid + 1] <= i) lo = mid + 1; else hi = mid;
            }
            const int s = lo, j = i - pref[s];
            const float stt = ss[b * Sn + s];
            if (j < nfs[s]) {
                const int fi = vvf[s] ? ws[OFF_PFIRST + qps[s] * 64 + j]
                                      : sfx[s * 64 + j];
                sc = stt * fsc[fi];
            } else {
                int jr = j - nfs[s];
                int wz = 0;
                while (jr >= segc[wz][s]) { jr -= segc[wz][s]; wz++; }
                sc = stt * rsc[seg[wz][s][jr]];
            }
        }
        outp[Bn * Sn * Gn * 3 + b * Sn + t] = sc;
    }
}

extern "C" void kernel_launch(void* const* d_in, const int* in_sizes, int n_in,
                              void* d_out, int out_size, void* d_ws, size_t ws_size,
                              hipStream_t stream) {
    const int*   goals  = (const int*)  d_in[0];
    const float* ss     = (const float*)d_in[1];
    const int*   facts  = (const int*)  d_in[2];
    const float* fsc    = (const float*)d_in[3];
    const int*   heads  = (const int*)  d_in[4];
    const int*   bodies = (const int*)  d_in[5];
    const int*   rlens  = (const int*)  d_in[6];
    const float* rsc    = (const float*)d_in[7];
    int*   ws   = (int*)d_ws;
    float* outp = (float*)d_out;

    probe_kernel   <<<NBLK + 50, 256, 0, stream>>>(goals, facts, ws);
    finalize_kernel<<<Bn,        256, 0, stream>>>(goals, ss, facts, fsc, heads,
                                                   bodies, rlens, rsc, ws, outp);
}

// Round 4
// 94.274 us; speedup vs baseline: 1.7179x; 1.0163x over previous
//
#include <hip/hip_runtime.h>

#define PAD 0
#define CONST_NO 10000
#define Bn 8
#define Sn 64
#define Gn 8
#define Fn 200000
#define Rn 200
#define BMAXn 3
#define KF 64
#define KR 32

#define NBLK 196
#define CHB  1024

// ---- workspace layout (ints) ----
#define OFF_CNTF   0                    // 512: per-state unordered match count
#define OFF_PN     512                  // 64 : per-predicate min(count,64)
#define OFF_PFIRST 1024                 // 64*64: first-64 fact idx per predicate
#define OFF_UF     5120                 // 512*64: unordered fact idx per state

__device__ __forceinline__ bool isv(int x) { return x > CONST_NO; }

// ---------- fused: blocks [0,196) probe facts vs const-queries;
//                   blocks [196,246) collect first-64 per predicate ----------
__global__ __launch_bounds__(256) void probe_kernel(
    const int* __restrict__ goals, const int* __restrict__ facts,
    int* __restrict__ ws)
{
    const int t = threadIdx.x;
    const int lane = t & 63, wv = t >> 6;

    if (blockIdx.x < NBLK) {
        // ================= probe role =================
        __shared__ int4 qlist[512];
        __shared__ int qcnt[64], qstart[64];
        const int B = blockIdx.x;

        if (t < 64) qcnt[t] = 0;
        __syncthreads();

        // stage the 512 queries, bucketed by predicate (const-arg queries only)
        // goal rows are 96 B (16B-aligned): one int4 grabs qp,qa0,qa1
        int myPos[2], myQp[2], myQv[2], myQm[2], mySt[2];
        #pragma unroll
        for (int k = 0; k < 2; ++k) {
            const int s = t + k * 256;
            const int4 h = *(const int4*)(goals + s * (Gn * 3));
            const int qp = h.x, qa0 = h.y, qa1 = h.z;
            const bool v0 = isv(qa0), v1 = isv(qa1);
            const bool use = (qp != PAD) && !(v0 && v1);
            myQp[k] = use ? qp : -1;
            myQv[k] = (v0 ? 0 : (qa0 << 14)) | (v1 ? 0 : qa1);
            myQm[k] = (v0 ? 0 : (0x3FFF << 14)) | (v1 ? 0 : 0x3FFF);
            mySt[k] = s;
            myPos[k] = use ? atomicAdd(&qcnt[qp], 1) : -1;
        }
        __syncthreads();
        if (t < 64) {
            const int v = qcnt[t];
            int incl = v;
            #pragma unroll
            for (int off = 1; off < 64; off <<= 1) {
                int n = __shfl_up(incl, off, 64);
                if (t >= off) incl += n;
            }
            qstart[t] = incl - v;
        }
        __syncthreads();
        #pragma unroll
        for (int k = 0; k < 2; ++k)
            if (myQp[k] >= 0)
                qlist[qstart[myQp[k]] + myPos[k]] =
                    make_int4(myQv[k], myQm[k], mySt[k], 0);
        __syncthreads();

        // stream this block's 1024 facts; compare against the predicate bucket
        const int f0 = B * CHB + t * 4;
        int pv[4], pk[4];
        if (f0 + 3 < Fn) {
            const int4* p4 = (const int4*)(facts + 3 * f0);
            int4 a = p4[0], b4 = p4[1], c4 = p4[2];
            pv[0] = a.x;  pk[0] = (a.y  << 14) | a.z;
            pv[1] = a.w;  pk[1] = (b4.x << 14) | b4.y;
            pv[2] = b4.z; pk[2] = (b4.w << 14) | c4.x;
            pv[3] = c4.y; pk[3] = (c4.z << 14) | c4.w;
        } else {
            #pragma unroll
            for (int u = 0; u < 4; ++u) {
                pv[u] = -1; pk[u] = 0;
                if (f0 + u < Fn) {
                    pv[u] = facts[3 * (f0 + u)];
                    pk[u] = (facts[3 * (f0 + u) + 1] << 14) | facts[3 * (f0 + u) + 2];
                }
            }
        }
        #pragma unroll
        for (int u = 0; u < 4; ++u) {
            if (pv[u] >= 0) {
                const int j0 = qstart[pv[u]], j1 = j0 + qcnt[pv[u]];
                for (int j = j0; j < j1; ++j) {
                    const int4 qq = qlist[j];
                    if (((pk[u] ^ qq.x) & qq.y) == 0) {
                        const int pos = atomicAdd(ws + OFF_CNTF + qq.z, 1);
                        if (pos < KF) ws[OFF_UF + qq.z * KF + pos] = f0 + u;
                    }
                }
            }
        }
    } else {
        // ================= first-64-per-predicate role =================
        __shared__ int wave_tot[4];
        const int p = blockIdx.x - NBLK + 1;       // predicate 1..50

        int total = 0;
        for (int base = 0; base < Fn && total < KF; base += 1024) {
            const int f0 = base + t * 4;
            unsigned mbits = 0;
            if (f0 + 3 < Fn) {
                const int4* p4 = (const int4*)(facts + 3 * f0);
                int4 a = p4[0], b4 = p4[1], c4 = p4[2];
                if (a.x  == p) mbits |= 1u;
                if (a.w  == p) mbits |= 2u;
                if (b4.z == p) mbits |= 4u;
                if (c4.y == p) mbits |= 8u;
            } else {
                #pragma unroll
                for (int u = 0; u < 4; ++u)
                    if (f0 + u < Fn && facts[3 * (f0 + u)] == p) mbits |= (1u << u);
            }
            const int c4n = __popc(mbits);

            int v = c4n;
            #pragma unroll
            for (int off = 1; off < 64; off <<= 1) {
                int n = __shfl_up(v, off, 64);
                if (lane >= off) v += n;
            }
            if (lane == 63) wave_tot[wv] = v;
            __syncthreads();
            int excl = v - c4n;
            #pragma unroll
            for (int w = 0; w < 4; ++w) if (w < wv) excl += wave_tot[w];
            const int ctot = wave_tot[0] + wave_tot[1] + wave_tot[2] + wave_tot[3];

            int pos = total + excl;
            #pragma unroll
            for (int u = 0; u < 4; ++u) {
                if (mbits & (1u << u)) {
                    if (pos < KF) ws[OFF_PFIRST + p * 64 + pos] = f0 + u;
                    pos++;
                }
            }
            total += ctot;
            __syncthreads();
        }
        if (t == 0) ws[OFF_PN + p] = (total < KF) ? total : KF;
    }
}

// ---------- finalize + select: one block per batch ----------
__global__ __launch_bounds__(256) void finalize_kernel(
    const int* __restrict__ goals, const float* __restrict__ ss,
    const int* __restrict__ facts, const float* __restrict__ fsc,
    const int* __restrict__ heads, const int* __restrict__ bodies,
    const int* __restrict__ rlens, const float* __restrict__ rsc,
    const int* __restrict__ ws, float* __restrict__ outp)
{
    __shared__ int sfx[Sn * 64];        // 16 KB: sorted fact idx (const states)
    __shared__ int seg[4][Sn][16];      // 16 KB: rule segments (50 rules each)
    __shared__ int segc[4][Sn];
    __shared__ int hds[Rn * 3];
    __shared__ int pref[Sn + 1];
    __shared__ int nfs[Sn], vvf[Sn], qps[Sn];

    const int b = blockIdx.x, t = threadIdx.x;
    const int lane = t & 63, wv = t >> 6;

    for (int k = t; k < Rn * 3; k += 256) hds[k] = heads[k];
    segc[wv][lane] = 0;   // 4*64 == 256 == blockDim
    __syncthreads();

    // rules: wave wv checks rules [wv*50, wv*50+50) for state s=lane
    {
        const int s = lane;
        const int4 h = *(const int4*)(goals + (b * Sn + s) * (Gn * 3));
        const int qp = h.x, qa0 = h.y, qa1 = h.z;
        const bool v0 = isv(qa0), v1 = isv(qa1);
        const bool active = (qp != PAD);
        int cnt = 0;
        const int r0 = wv * 50;
        for (int r = r0; r < r0 + 50; ++r) {
            const int h0 = hds[3 * r], h1 = hds[3 * r + 1], h2 = hds[3 * r + 2];
            if (active && h0 == qp && (isv(h1) || v0 || qa0 == h1)
                                   && (isv(h2) || v1 || qa1 == h2)) {
                if (cnt < 16) seg[wv][s][cnt] = r;
                cnt++;
            }
        }
        segc[wv][s] = (cnt < 16) ? cnt : 16;
    }
    __syncthreads();

    // per-state fact lists + prefix
    if (t < Sn) {
        const int s = t;
        const int4 h = *(const int4*)(goals + (b * Sn + s) * (Gn * 3));
        const int qp = h.x, qa0 = h.y, qa1 = h.z;
        const bool v0 = isv(qa0), v1 = isv(qa1);
        const bool active = (qp != PAD);
        const bool vv = active && v0 && v1;
        int nf = 0;
        if (vv) {
            nf = ws[OFF_PN + qp];
        } else if (active) {
            int c = ws[OFF_CNTF + b * Sn + s];
            if (c > KF) c = KF;
            for (int j = 0; j < c; ++j)
                sfx[s * 64 + j] = ws[OFF_UF + (b * Sn + s) * KF + j];
            // insertion sort ascending (reference order = ascending fact idx)
            for (int a = 1; a < c; ++a) {
                const int key = sfx[s * 64 + a];
                int m = a - 1;
                while (m >= 0 && sfx[s * 64 + m] > key) {
                    sfx[s * 64 + m + 1] = sfx[s * 64 + m];
                    m--;
                }
                sfx[s * 64 + m + 1] = key;
            }
            nf = c;
        }
        nfs[s] = nf;
        vvf[s] = vv ? 1 : 0;
        qps[s] = qp;
        int nr = segc[0][s] + segc[1][s] + segc[2][s] + segc[3][s];
        if (nr > KR) nr = KR;

        int incl = nf + nr;
        #pragma unroll
        for (int off = 1; off < 64; off <<= 1) {
            int n = __shfl_up(incl, off, 64);
            if (t >= off) incl += n;
        }
        pref[s + 1] = incl;
        if (s == 0) pref[0] = 0;
    }
    __syncthreads();
    const int total = pref[Sn];

    // emit goals: 64 slots x 8 positions = 512 items, 2 per thread
    for (int item = t; item < Sn * Gn; item += 256) {
        const int i = item >> 3, g = item & 7;
        int trip[3] = {PAD, PAD, PAD};
        if (i < total) {
            int lo = 0, hi = Sn - 1;
            while (lo < hi) {
                const int mid = (lo + hi) >> 1;
                if (pref[mid + 1] <= i) lo = mid + 1; else hi = mid;
            }
            const int s = lo, j = i - pref[s];
            const int* q = goals + (b * Sn + s) * (Gn * 3);
            const int qa0 = q[1], qa1 = q[2];
            if (j < nfs[s]) {
                const int fi = vvf[s] ? ws[OFF_PFIRST + qps[s] * 64 + j]
                                      : sfx[s * 64 + j];
                const int f1 = facts[3 * fi + 1], f2 = facts[3 * fi + 2];
                if (g >= 1) {
                    #pragma unroll
                    for (int c = 0; c < 3; ++c) {
                        int x = q[g * 3 + c];
                        if (isv(qa0) && x == qa0) x = f1;
                        else if (isv(qa1) && x == qa1) x = f2;
                        trip[c] = x;
                    }
                }
            } else {
                int jr = j - nfs[s];
                int wz = 0;
                while (jr >= segc[wz][s]) { jr -= segc[wz][s]; wz++; }
                const int ri = seg[wz][s][jr];
                const int h1 = hds[3 * ri + 1], h2 = hds[3 * ri + 2];
                const int len = rlens[ri];
                if (g < BMAXn) {
                    if (g < len) {
                        #pragma unroll
                        for (int c = 0; c < 3; ++c) {
                            int x = bodies[(ri * BMAXn + g) * 3 + c];
                            if (isv(h1) && x == h1) x = qa0;
                            if (isv(h2) && x == h2) x = qa1;
                            trip[c] = x;
                        }
                    }
                } else {
                    trip[0] = q[(g - 2) * 3 + 0];
                    trip[1] = q[(g - 2) * 3 + 1];
                    trip[2] = q[(g - 2) * 3 + 2];
                }
            }
        }
        float* o = outp + ((b * Sn + i) * Gn + g) * 3;
        o[0] = (float)trip[0];
        o[1] = (float)trip[1];
        o[2] = (float)trip[2];
    }

    // scores
    if (t < Sn) {
        const int i = t;
        float sc = 0.f;
        if (i < total) {
            int lo = 0, hi = Sn - 1;
            while (lo < hi) {
                const int mid = (lo + hi) >> 1;
                if (pref[mid + 1] <= i) lo = mid + 1; else hi = mid;
            }
            const int s = lo, j = i - pref[s];
            const float stt = ss[b * Sn + s];
            if (j < nfs[s]) {
                const int fi = vvf[s] ? ws[OFF_PFIRST + qps[s] * 64 + j]
                                      : sfx[s * 64 + j];
                sc = stt * fsc[fi];
            } else {
                int jr = j - nfs[s];
                int wz = 0;
                while (jr >= segc[wz][s]) { jr -= segc[wz][s]; wz++; }
                sc = stt * rsc[seg[wz][s][jr]];
            }
        }
        outp[Bn * Sn * Gn * 3 + b * Sn + t] = sc;
    }
}

extern "C" void kernel_launch(void* const* d_in, const int* in_sizes, int n_in,
                              void* d_out, int out_size, void* d_ws, size_t ws_size,
                              hipStream_t stream) {
    const int*   goals  = (const int*)  d_in[0];
    const float* ss     = (const float*)d_in[1];
    const int*   facts  = (const int*)  d_in[2];
    const float* fsc    = (const float*)d_in[3];
    const int*   heads  = (const int*)  d_in[4];
    const int*   bodies = (const int*)  d_in[5];
    const int*   rlens  = (const int*)  d_in[6];
    const float* rsc    = (const float*)d_in[7];
    int*   ws   = (int*)d_ws;
    float* outp = (float*)d_out;

    hipMemsetAsync(ws, 0, 512 * sizeof(int), stream);           // zero cntF
    probe_kernel   <<<NBLK + 50, 256, 0, stream>>>(goals, facts, ws);
    finalize_kernel<<<Bn,        256, 0, stream>>>(goals, ss, facts, fsc, heads,
                                                   bodies, rlens, rsc, ws, outp);
}